// Round 1
// baseline (1339.692 us; speedup 1.0000x reference)
//
#include <hip/hip_runtime.h>
#include <math.h>

// FNO2d: B=8, H=W=128, WIDTH=32, MODES=12, NL=6
// Spectral conv via partial DFT (only 12x12 corner modes x2 halves survive).

#define NBATCH 8
#define NL 6

__device__ __forceinline__ float gelu_f(float x){
  return 0.5f*x*(1.0f + erff(x*0.70710678118654752f));
}

// ---------------- fc0: x[B,H,W,4] @ [4,32] + b -> y[B,32,H,W] ----------------
__global__ __launch_bounds__(256) void k_fc0(const float* __restrict__ x,
                      const float* __restrict__ W, const float* __restrict__ b,
                      float* __restrict__ y){
  __shared__ float Ws[128];
  __shared__ float bs[32];
  int t = threadIdx.x;
  if (t < 128) Ws[t] = W[t];
  if (t < 32)  bs[t] = b[t];
  __syncthreads();
  int pix = blockIdx.x*256 + t;                  // 131072 pixels
  float4 xv = *reinterpret_cast<const float4*>(x + (size_t)pix*4);
  int bb = pix >> 14, hw = pix & 16383;
  float* yp = y + (size_t)bb*32*16384 + hw;
  #pragma unroll
  for (int c=0;c<32;c++){
    float acc = bs[c] + xv.x*Ws[c] + xv.y*Ws[32+c] + xv.z*Ws[64+c] + xv.w*Ws[96+c];
    yp[(size_t)c*16384] = acc;
  }
}

// ---------------- stage A: DFT along W, 12 kx modes -------------------------
// y rows (b,c,h)[128] -> F1[bc][kx12][ri2][h128]
__global__ __launch_bounds__(256) void k_dftw(const float* __restrict__ y, float* __restrict__ F1){
  __shared__ float xs[32][129];
  __shared__ float twc[128], tws[128];
  int t=threadIdx.x;
  if (t<128){ float s,c; sincospif(t*(1.0f/64.0f), &s, &c); twc[t]=c; tws[t]=s; }
  int row0 = blockIdx.x*32;                       // 32768 rows total, grid 1024
  for (int i=t;i<4096;i+=256){ int r=i>>7, w=i&127; xs[r][w] = y[(size_t)(row0+r)*128 + w]; }
  __syncthreads();
  for (int j=t;j<768;j+=256){
    int rl = j/24, rem = j%24, kx = rem>>1, ri = rem&1;
    float acc = 0.f;
    if (ri==0){
      for (int w=0;w<128;w++) acc += xs[rl][w]*twc[(kx*w)&127];
    } else {
      for (int w=0;w<128;w++) acc -= xs[rl][w]*tws[(kx*w)&127];
    }
    int row = row0+rl; int bc = row>>7, h = row&127;
    F1[((size_t)(bc*12+kx)*2+ri)*128 + h] = acc;
  }
}

// ---------------- stage B: DFT along H, 24 ky modes -------------------------
// F1[bc][kx][ri][h] -> F2[b][ky24][kx12][ri2][c32]
__global__ __launch_bounds__(256) void k_dfth(const float* __restrict__ F1, float* __restrict__ F2){
  __shared__ float fs[128][24];   // [h][kx*2+ri]
  __shared__ float twc[128], tws[128];
  int t=threadIdx.x;
  if (t<128){ float s,c; sincospif(t*(1.0f/64.0f), &s, &c); twc[t]=c; tws[t]=s; }
  int bc = blockIdx.x;                            // 256 blocks
  const float* src = F1 + (size_t)bc*3072;
  for (int i=t;i<3072;i+=256){ int kx=i>>8, ri=(i>>7)&1, h=i&127; fs[h][kx*2+ri] = src[i]; }
  __syncthreads();
  int b = bc>>5, c = bc&31;
  for (int j=t;j<576;j+=256){
    int ri=j&1, kxky=j>>1, kx=kxky%12, kyi=kxky/12;
    int ky = kyi<12 ? kyi : 104+kyi;              // 116..127
    float acc=0.f;
    if (ri==0){
      for (int h=0;h<128;h++){ int m=(ky*h)&127; acc += fs[h][kx*2]*twc[m] + fs[h][kx*2+1]*tws[m]; }
    } else {
      for (int h=0;h<128;h++){ int m=(ky*h)&127; acc += fs[h][kx*2+1]*twc[m] - fs[h][kx*2]*tws[m]; }
    }
    F2[(((size_t)(b*24+kyi)*12+kx)*2+ri)*32 + c] = acc;
  }
}

// ---------------- mode mix: complex [32]x[32,32] per (b,ky,kx) --------------
// F2[b][ky][kx][ri][c] x spec_w[l][half][i][o][kym][kx][ri] -> G[b][o][ky][kx][ri]
__global__ __launch_bounds__(256) void k_mix(const float* __restrict__ F2, const float* __restrict__ w,
                     float* __restrict__ G){
  __shared__ float fr[12][32], fi[12][32];
  int t=threadIdx.x;
  int b = blockIdx.x/24, kyi = blockIdx.x%24;     // 192 blocks
  const float* src = F2 + (size_t)(b*24+kyi)*768;
  for (int i=t;i<768;i+=256){ int kx=i>>6, ri=(i>>5)&1, cc=i&31;
    if(ri) fi[kx][cc]=src[i]; else fr[kx][cc]=src[i]; }
  __syncthreads();
  int half = kyi<12?0:1, kym = kyi<12?kyi:kyi-12;
  const float* wbase = w + (size_t)half*294912 + kym*24;
  for (int j=t;j<384;j+=256){
    int kx=j%12, o=j/12;
    const float* wp = wbase + o*288 + kx*2;
    float gr=0.f, gi=0.f;
    #pragma unroll 8
    for (int i=0;i<32;i++){
      float wr = wp[(size_t)i*9216], wi = wp[(size_t)i*9216+1];
      float ar = fr[kx][i], ai = fi[kx][i];
      gr += ar*wr - ai*wi;
      gi += ar*wi + ai*wr;
    }
    size_t gidx = (((size_t)(b*32+o)*24+kyi)*12+kx)*2;
    G[gidx]=gr; G[gidx+1]=gi;
  }
}

// ---------------- stage C: inverse DFT along H (scaled by 1/(H*W)) ----------
// G[b][o][ky][kx][ri] -> S1[b][o][h][kx][ri]
__global__ __launch_bounds__(256) void k_idfth(const float* __restrict__ G, float* __restrict__ S1){
  __shared__ float gr[24][12], gi[24][12];
  __shared__ float twc[128], tws[128];
  int t=threadIdx.x;
  if (t<128){ float s,c; sincospif(t*(1.0f/64.0f), &s, &c); twc[t]=c; tws[t]=s; }
  int bo = blockIdx.x;                            // 256 blocks
  const float* src = G + (size_t)bo*576;
  for (int i=t;i<576;i+=256){ int kyi=i/24, rem=i%24, kx=rem>>1;
    if(rem&1) gi[kyi][kx]=src[i]; else gr[kyi][kx]=src[i]; }
  __syncthreads();
  float* dst = S1 + (size_t)bo*3072;
  for (int j=t;j<1536;j+=256){
    int h=j/12, kx=j%12;
    float sr=0.f, si=0.f;
    #pragma unroll
    for (int k=0;k<24;k++){
      int ky = k<12?k:104+k;
      int m=(ky*h)&127;
      float cc=twc[m], ss=tws[m];
      float a=gr[k][kx], bi=gi[k][kx];
      sr += a*cc - bi*ss;
      si += a*ss + bi*cc;
    }
    dst[(h*12+kx)*2]   = sr*(1.0f/16384.0f);
    dst[(h*12+kx)*2+1] = si*(1.0f/16384.0f);
  }
}

// ---------------- combine: spec + conv1x1(y) + bias(grid,mesh), GELU --------
__global__ __launch_bounds__(256) void k_combine(const float* __restrict__ yin, const float* __restrict__ S1,
                         const float* __restrict__ x,
                         const float* __restrict__ wWl, const float* __restrict__ wbl,
                         const float* __restrict__ bWl, const float* __restrict__ bbl,
                         const float* __restrict__ cWl, const float* __restrict__ cbl,
                         float* __restrict__ yout){
  __shared__ float ys[32][128];
  __shared__ float s1[32][24];
  __shared__ float Wsh[32][33];
  __shared__ float twc[128], tws[128];
  int t=threadIdx.x;
  if (t<128){ float s,c; sincospif(t*(1.0f/64.0f), &s, &c); twc[t]=c; tws[t]=s; }
  int b = blockIdx.x>>7, h = blockIdx.x&127;      // 1024 blocks
  for (int i=t;i<4096;i+=256){ int c=i>>7, w=i&127;
    ys[c][w]=yin[(((size_t)(b*32+c))*128+h)*128+w]; }
  for (int i=t;i<768;i+=256){ int o=i/24, rem=i%24;
    s1[o][rem]=S1[((size_t)(b*32+o)*128+h)*24+rem]; }
  for (int i=t;i<1024;i+=256){ Wsh[i>>5][i&31]=wWl[i]; }
  __syncthreads();
  int w = t&127, og = t>>7;
  float gx = h*(1.0f/127.0f), gy = w*(1.0f/127.0f);
  const float* xp = x + (((size_t)(b*128+h))*128+w)*4;
  float m1=xp[1], m2=xp[2], m3=xp[3];
  float ct[12], st[12];
  #pragma unroll
  for (int kx=0;kx<12;kx++){ int m=(kx*w)&127; ct[kx]=twc[m]; st[kx]=tws[m]; }
  for (int oi=0;oi<16;oi++){
    int o = og + oi*2;
    float spec = s1[o][0];
    #pragma unroll
    for (int kx=1;kx<12;kx++) spec += 2.0f*(s1[o][kx*2]*ct[kx] - s1[o][kx*2+1]*st[kx]);
    float acc = wbl[o] + bbl[o] + cbl[o] + gx*bWl[o*2] + gy*bWl[o*2+1]
              + m1*cWl[o*3] + m2*cWl[o*3+1] + m3*cWl[o*3+2];
    #pragma unroll 8
    for (int c=0;c<32;c++) acc += Wsh[o][c]*ys[c][w];
    float z = spec + acc;
    yout[(((size_t)(b*32+o))*128+h)*128+w] = gelu_f(z);
  }
}

// ---------------- head GEMM 1: y[b,c,hw] (c-major) -> A1[pix,256], GELU -----
__global__ __launch_bounds__(256) void k_head1(const float* __restrict__ y, const float* __restrict__ W,
                       const float* __restrict__ bias, float* __restrict__ out, int pix0){
  __shared__ __align__(16) float As[32][68];
  __shared__ __align__(16) float Bs[32][68];
  int t=threadIdx.x;
  int pg = pix0 + blockIdx.x*64;
  int b = pg>>14, hw0 = pg&16383;
  int n0 = blockIdx.y*64;
  for (int i=t;i<2048;i+=256){ int k=i>>6, pl=i&63;
    As[k][pl] = y[((size_t)(b*32+k))*16384 + hw0 + pl]; }
  for (int i=t;i<2048;i+=256){ int k=i>>6, n=i&63;
    Bs[k][n] = W[(size_t)k*256 + n0 + n]; }
  __syncthreads();
  int tx=t&15, ty=t>>4;
  float acc[4][4];
  #pragma unroll
  for (int i=0;i<4;i++){ acc[i][0]=0.f; acc[i][1]=0.f; acc[i][2]=0.f; acc[i][3]=0.f; }
  #pragma unroll 8
  for (int k=0;k<32;k++){
    float4 av = *reinterpret_cast<const float4*>(&As[k][ty*4]);
    float4 bv = *reinterpret_cast<const float4*>(&Bs[k][tx*4]);
    acc[0][0]+=av.x*bv.x; acc[0][1]+=av.x*bv.y; acc[0][2]+=av.x*bv.z; acc[0][3]+=av.x*bv.w;
    acc[1][0]+=av.y*bv.x; acc[1][1]+=av.y*bv.y; acc[1][2]+=av.y*bv.z; acc[1][3]+=av.y*bv.w;
    acc[2][0]+=av.z*bv.x; acc[2][1]+=av.z*bv.y; acc[2][2]+=av.z*bv.z; acc[2][3]+=av.z*bv.w;
    acc[3][0]+=av.w*bv.x; acc[3][1]+=av.w*bv.y; acc[3][2]+=av.w*bv.z; acc[3][3]+=av.w*bv.w;
  }
  #pragma unroll
  for (int i=0;i<4;i++){
    int pl = blockIdx.x*64 + ty*4 + i;
    #pragma unroll
    for (int j=0;j<4;j++){
      int n = n0 + tx*4 + j;
      float v = acc[i][j] + bias[n];
      out[(size_t)pl*256 + n] = gelu_f(v);
    }
  }
}

// ---------------- generic head GEMM: A[P,K] @ W[K,N] + bias ----------------
template<int K, int N, bool GELU>
__global__ __launch_bounds__(256) void k_mlp(const float* __restrict__ A, const float* __restrict__ W,
                     const float* __restrict__ bias, float* __restrict__ out){
  __shared__ __align__(16) float As[32][68];
  __shared__ __align__(16) float Bs[32][68];
  int t=threadIdx.x;
  int p0 = blockIdx.x*64;
  int n0 = blockIdx.y*64;
  int tx=t&15, ty=t>>4;
  float acc[4][4];
  #pragma unroll
  for (int i=0;i<4;i++){ acc[i][0]=0.f; acc[i][1]=0.f; acc[i][2]=0.f; acc[i][3]=0.f; }
  for (int kc=0;kc<K;kc+=32){
    for (int i=t;i<2048;i+=256){ int pl=i>>5, k=i&31;
      As[k][pl]=A[(size_t)(p0+pl)*K + kc + k]; }
    for (int i=t;i<2048;i+=256){ int k=i>>6, n=i&63;
      Bs[k][n]=W[(size_t)(kc+k)*N + n0 + n]; }
    __syncthreads();
    #pragma unroll 8
    for (int k=0;k<32;k++){
      float4 av = *reinterpret_cast<const float4*>(&As[k][ty*4]);
      float4 bv = *reinterpret_cast<const float4*>(&Bs[k][tx*4]);
      acc[0][0]+=av.x*bv.x; acc[0][1]+=av.x*bv.y; acc[0][2]+=av.x*bv.z; acc[0][3]+=av.x*bv.w;
      acc[1][0]+=av.y*bv.x; acc[1][1]+=av.y*bv.y; acc[1][2]+=av.y*bv.z; acc[1][3]+=av.y*bv.w;
      acc[2][0]+=av.z*bv.x; acc[2][1]+=av.z*bv.y; acc[2][2]+=av.z*bv.z; acc[2][3]+=av.z*bv.w;
      acc[3][0]+=av.w*bv.x; acc[3][1]+=av.w*bv.y; acc[3][2]+=av.w*bv.z; acc[3][3]+=av.w*bv.w;
    }
    __syncthreads();
  }
  #pragma unroll
  for (int i=0;i<4;i++){
    int p = p0 + ty*4 + i;
    #pragma unroll
    for (int j=0;j<4;j++){
      int n = n0 + tx*4 + j;
      float v = acc[i][j] + bias[n];
      if (GELU) v = gelu_f(v);
      out[(size_t)p*N + n] = v;
    }
  }
}

// ---------------- fc5: [P,128] @ [128,1] + b ---------------------------------
__global__ __launch_bounds__(256) void k_fc5(const float* __restrict__ A, const float* __restrict__ W,
                     const float* __restrict__ bias, float* __restrict__ out){
  __shared__ float As[64][129];
  __shared__ float ws[128];
  int t=threadIdx.x;
  if (t<128) ws[t]=W[t];
  int p0 = blockIdx.x*64;
  for (int i=t;i<8192;i+=256){ int pl=i>>7, k=i&127; As[pl][k]=A[(size_t)(p0+pl)*128 + k]; }
  __syncthreads();
  int pl=t>>2, q=t&3;
  float acc=0.f;
  #pragma unroll 8
  for (int k=0;k<32;k++) acc += As[pl][q*32+k]*ws[q*32+k];
  acc += __shfl_down(acc,1,4);
  acc += __shfl_down(acc,2,4);
  if (q==0) out[p0+pl] = acc + bias[0];
}

extern "C" void kernel_launch(void* const* d_in, const int* in_sizes, int n_in,
                              void* d_out, int out_size, void* d_ws, size_t ws_size,
                              hipStream_t stream){
  const float* x     = (const float*)d_in[0];
  const float* fc0_W = (const float*)d_in[1];
  const float* fc0_b = (const float*)d_in[2];
  const float* spec_w= (const float*)d_in[3];
  const float* wW    = (const float*)d_in[4];
  const float* wb    = (const float*)d_in[5];
  const float* bW    = (const float*)d_in[6];
  const float* bb    = (const float*)d_in[7];
  const float* cW    = (const float*)d_in[8];
  const float* cb    = (const float*)d_in[9];
  const float* fc1_W = (const float*)d_in[10];
  const float* fc1_b = (const float*)d_in[11];
  const float* fc3_W = (const float*)d_in[12];
  const float* fc3_b = (const float*)d_in[13];
  const float* fc4_W = (const float*)d_in[14];
  const float* fc4_b = (const float*)d_in[15];
  const float* fc5_W = (const float*)d_in[16];
  const float* fc5_b = (const float*)d_in[17];
  float* out = (float*)d_out;
  float* ws  = (float*)d_ws;

  float* y_a = ws;                       // 4,194,304
  float* y_b = y_a + 4194304;            // 4,194,304
  float* F1  = y_b + 4194304;            //   786,432
  float* F2  = F1 + 786432;              //   147,456
  float* G   = F2 + 147456;              //   147,456
  float* S1  = G  + 147456;              //   786,432
  float* HD  = S1 + 786432;              // head buffers start (10,256,384 floats in)

  k_fc0<<<512,256,0,stream>>>(x, fc0_W, fc0_b, y_a);

  for (int l=0;l<NL;l++){
    float* yin  = (l&1)? y_b : y_a;
    float* yout = (l&1)? y_a : y_b;
    k_dftw<<<1024,256,0,stream>>>(yin, F1);
    k_dfth<<<256,256,0,stream>>>(F1, F2);
    k_mix<<<192,256,0,stream>>>(F2, spec_w + (size_t)l*589824, G);
    k_idfth<<<256,256,0,stream>>>(G, S1);
    k_combine<<<1024,256,0,stream>>>(yin, S1, x,
                                     wW + (size_t)l*1024, wb + (size_t)l*32,
                                     bW + (size_t)l*64,  bb + (size_t)l*32,
                                     cW + (size_t)l*96,  cb + (size_t)l*32, yout);
  }
  float* yfin = y_a;  // after even number (6) of layers

  // head: choose full-width (better occupancy) if workspace allows
  const size_t full_need = (size_t)(10256384 + 33554432 + 16777216 + 16777216) * 4;
  if (ws_size >= full_need){
    float* A1 = HD;                // 131072*256
    float* A2 = A1 + 33554432;     // 131072*128
    float* A3 = A2 + 16777216;     // 131072*128
    dim3 g1(2048,4); k_head1<<<g1,256,0,stream>>>(yfin, fc1_W, fc1_b, A1, 0);
    dim3 g2(2048,2); k_mlp<256,128,true ><<<g2,256,0,stream>>>(A1, fc3_W, fc3_b, A2);
    dim3 g3(2048,2); k_mlp<128,128,false><<<g3,256,0,stream>>>(A2, fc4_W, fc4_b, A3);
    k_fc5<<<2048,256,0,stream>>>(A3, fc5_W, fc5_b, out);
  } else {
    // per-batch chunks (16384 pixels each)
    float* A1 = HD;                // 16384*256
    float* A2 = A1 + 4194304;      // 16384*128
    float* A3 = A2 + 2097152;      // 16384*128
    for (int bi=0; bi<NBATCH; bi++){
      dim3 g1(256,4); k_head1<<<g1,256,0,stream>>>(yfin, fc1_W, fc1_b, A1, bi*16384);
      dim3 g2(256,2); k_mlp<256,128,true ><<<g2,256,0,stream>>>(A1, fc3_W, fc3_b, A2);
      dim3 g3(256,2); k_mlp<128,128,false><<<g3,256,0,stream>>>(A2, fc4_W, fc4_b, A3);
      k_fc5<<<256,256,0,stream>>>(A3, fc5_W, fc5_b, out + (size_t)bi*16384);
    }
  }
}

// Round 2
// 961.443 us; speedup vs baseline: 1.3934x; 1.3934x over previous
//
#include <hip/hip_runtime.h>
#include <math.h>

// FNO2d: B=8, H=W=128, WIDTH=32, MODES=12, NL=6
// Spectral conv via partial DFT (only 12x12 corner modes x2 halves survive).

#define NBATCH 8
#define NL 6

__device__ __forceinline__ float gelu_f(float x){
  return 0.5f*x*(1.0f + erff(x*0.70710678118654752f));
}

// ---------------- fc0: x[B,H,W,4] @ [4,32] + b -> y[B,32,H,W] ----------------
__global__ __launch_bounds__(256) void k_fc0(const float* __restrict__ x,
                      const float* __restrict__ W, const float* __restrict__ b,
                      float* __restrict__ y){
  __shared__ float Ws[128];
  __shared__ float bs[32];
  int t = threadIdx.x;
  if (t < 128) Ws[t] = W[t];
  if (t < 32)  bs[t] = b[t];
  __syncthreads();
  int pix = blockIdx.x*256 + t;                  // 131072 pixels
  float4 xv = *reinterpret_cast<const float4*>(x + (size_t)pix*4);
  int bb = pix >> 14, hw = pix & 16383;
  float* yp = y + (size_t)bb*32*16384 + hw;
  #pragma unroll
  for (int c=0;c<32;c++){
    float acc = bs[c] + xv.x*Ws[c] + xv.y*Ws[32+c] + xv.z*Ws[64+c] + xv.w*Ws[96+c];
    yp[(size_t)c*16384] = acc;
  }
}

// ---------------- stage A: DFT along W, 12 kx modes -------------------------
// y rows (b,c,h)[128] -> F1[bc][kx12][ri2][h128]
__global__ __launch_bounds__(256) void k_dftw(const float* __restrict__ y, float* __restrict__ F1){
  __shared__ float xs[32][129];
  __shared__ float twc[128], tws[128];
  int t=threadIdx.x;
  if (t<128){ float s,c; sincospif(t*(1.0f/64.0f), &s, &c); twc[t]=c; tws[t]=s; }
  int row0 = blockIdx.x*32;                       // 32768 rows total, grid 1024
  for (int i=t;i<4096;i+=256){ int r=i>>7, w=i&127; xs[r][w] = y[(size_t)(row0+r)*128 + w]; }
  __syncthreads();
  for (int j=t;j<768;j+=256){
    int rl = j/24, rem = j%24, kx = rem>>1, ri = rem&1;
    float acc = 0.f;
    if (ri==0){
      for (int w=0;w<128;w++) acc += xs[rl][w]*twc[(kx*w)&127];
    } else {
      for (int w=0;w<128;w++) acc -= xs[rl][w]*tws[(kx*w)&127];
    }
    int row = row0+rl; int bc = row>>7, h = row&127;
    F1[((size_t)(bc*12+kx)*2+ri)*128 + h] = acc;
  }
}

// ---------------- stage B: DFT along H, 24 ky modes -------------------------
// F1[bc][kx][ri][h] -> F2[b][ky24][kx12][ri2][c32]
__global__ __launch_bounds__(256) void k_dfth(const float* __restrict__ F1, float* __restrict__ F2){
  __shared__ float fs[128][24];   // [h][kx*2+ri]
  __shared__ float twc[128], tws[128];
  int t=threadIdx.x;
  if (t<128){ float s,c; sincospif(t*(1.0f/64.0f), &s, &c); twc[t]=c; tws[t]=s; }
  int bc = blockIdx.x;                            // 256 blocks
  const float* src = F1 + (size_t)bc*3072;
  for (int i=t;i<3072;i+=256){ int kx=i>>8, ri=(i>>7)&1, h=i&127; fs[h][kx*2+ri] = src[i]; }
  __syncthreads();
  int b = bc>>5, c = bc&31;
  for (int j=t;j<576;j+=256){
    int ri=j&1, kxky=j>>1, kx=kxky%12, kyi=kxky/12;
    int ky = kyi<12 ? kyi : 104+kyi;              // 116..127
    float acc=0.f;
    if (ri==0){
      for (int h=0;h<128;h++){ int m=(ky*h)&127; acc += fs[h][kx*2]*twc[m] + fs[h][kx*2+1]*tws[m]; }
    } else {
      for (int h=0;h<128;h++){ int m=(ky*h)&127; acc += fs[h][kx*2+1]*twc[m] - fs[h][kx*2]*tws[m]; }
    }
    F2[(((size_t)(b*24+kyi)*12+kx)*2+ri)*32 + c] = acc;
  }
}

// ---------------- mode mix: complex [32]x[32,32] per (b,ky,kx) --------------
// F2[b][ky][kx][ri][c] x spec_w[l][half][i][o][kym][kx][ri] -> G[b][o][ky][kx][ri]
__global__ __launch_bounds__(256) void k_mix(const float* __restrict__ F2, const float* __restrict__ w,
                     float* __restrict__ G){
  __shared__ float fr[12][32], fi[12][32];
  int t=threadIdx.x;
  int b = blockIdx.x/24, kyi = blockIdx.x%24;     // 192 blocks
  const float* src = F2 + (size_t)(b*24+kyi)*768;
  for (int i=t;i<768;i+=256){ int kx=i>>6, ri=(i>>5)&1, cc=i&31;
    if(ri) fi[kx][cc]=src[i]; else fr[kx][cc]=src[i]; }
  __syncthreads();
  int half = kyi<12?0:1, kym = kyi<12?kyi:kyi-12;
  const float* wbase = w + (size_t)half*294912 + kym*24;
  for (int j=t;j<384;j+=256){
    int kx=j%12, o=j/12;
    const float* wp = wbase + o*288 + kx*2;
    float gr=0.f, gi=0.f;
    #pragma unroll 8
    for (int i=0;i<32;i++){
      float wr = wp[(size_t)i*9216], wi = wp[(size_t)i*9216+1];
      float ar = fr[kx][i], ai = fi[kx][i];
      gr += ar*wr - ai*wi;
      gi += ar*wi + ai*wr;
    }
    size_t gidx = (((size_t)(b*32+o)*24+kyi)*12+kx)*2;
    G[gidx]=gr; G[gidx+1]=gi;
  }
}

// ---------------- stage C: inverse DFT along H (scaled by 1/(H*W)) ----------
// G[b][o][ky][kx][ri] -> S1[b][o][h][kx][ri]
__global__ __launch_bounds__(256) void k_idfth(const float* __restrict__ G, float* __restrict__ S1){
  __shared__ float gr[24][12], gi[24][12];
  __shared__ float twc[128], tws[128];
  int t=threadIdx.x;
  if (t<128){ float s,c; sincospif(t*(1.0f/64.0f), &s, &c); twc[t]=c; tws[t]=s; }
  int bo = blockIdx.x;                            // 256 blocks
  const float* src = G + (size_t)bo*576;
  for (int i=t;i<576;i+=256){ int kyi=i/24, rem=i%24, kx=rem>>1;
    if(rem&1) gi[kyi][kx]=src[i]; else gr[kyi][kx]=src[i]; }
  __syncthreads();
  float* dst = S1 + (size_t)bo*3072;
  for (int j=t;j<1536;j+=256){
    int h=j/12, kx=j%12;
    float sr=0.f, si=0.f;
    #pragma unroll
    for (int k=0;k<24;k++){
      int ky = k<12?k:104+k;
      int m=(ky*h)&127;
      float cc=twc[m], ss=tws[m];
      float a=gr[k][kx], bi=gi[k][kx];
      sr += a*cc - bi*ss;
      si += a*ss + bi*cc;
    }
    dst[(h*12+kx)*2]   = sr*(1.0f/16384.0f);
    dst[(h*12+kx)*2+1] = si*(1.0f/16384.0f);
  }
}

// ---------------- combine: spec + conv1x1(y) + bias(grid,mesh), GELU --------
__global__ __launch_bounds__(256) void k_combine(const float* __restrict__ yin, const float* __restrict__ S1,
                         const float* __restrict__ x,
                         const float* __restrict__ wWl, const float* __restrict__ wbl,
                         const float* __restrict__ bWl, const float* __restrict__ bbl,
                         const float* __restrict__ cWl, const float* __restrict__ cbl,
                         float* __restrict__ yout){
  __shared__ float ys[32][128];
  __shared__ float s1[32][24];
  __shared__ float Wsh[32][33];
  __shared__ float twc[128], tws[128];
  int t=threadIdx.x;
  if (t<128){ float s,c; sincospif(t*(1.0f/64.0f), &s, &c); twc[t]=c; tws[t]=s; }
  int b = blockIdx.x>>7, h = blockIdx.x&127;      // 1024 blocks
  for (int i=t;i<4096;i+=256){ int c=i>>7, w=i&127;
    ys[c][w]=yin[(((size_t)(b*32+c))*128+h)*128+w]; }
  for (int i=t;i<768;i+=256){ int o=i/24, rem=i%24;
    s1[o][rem]=S1[((size_t)(b*32+o)*128+h)*24+rem]; }
  for (int i=t;i<1024;i+=256){ Wsh[i>>5][i&31]=wWl[i]; }
  __syncthreads();
  int w = t&127, og = t>>7;
  float gx = h*(1.0f/127.0f), gy = w*(1.0f/127.0f);
  const float* xp = x + (((size_t)(b*128+h))*128+w)*4;
  float m1=xp[1], m2=xp[2], m3=xp[3];
  float ct[12], st[12];
  #pragma unroll
  for (int kx=0;kx<12;kx++){ int m=(kx*w)&127; ct[kx]=twc[m]; st[kx]=tws[m]; }
  for (int oi=0;oi<16;oi++){
    int o = og + oi*2;
    float spec = s1[o][0];
    #pragma unroll
    for (int kx=1;kx<12;kx++) spec += 2.0f*(s1[o][kx*2]*ct[kx] - s1[o][kx*2+1]*st[kx]);
    float acc = wbl[o] + bbl[o] + cbl[o] + gx*bWl[o*2] + gy*bWl[o*2+1]
              + m1*cWl[o*3] + m2*cWl[o*3+1] + m3*cWl[o*3+2];
    #pragma unroll 8
    for (int c=0;c<32;c++) acc += Wsh[o][c]*ys[c][w];
    float z = spec + acc;
    yout[(((size_t)(b*32+o))*128+h)*128+w] = gelu_f(z);
  }
}

// ---------------- head GEMM 1: y[b,c,hw] (c-major) -> A1[pix,256], GELU -----
__global__ __launch_bounds__(256) void k_head1(const float* __restrict__ y, const float* __restrict__ W,
                       const float* __restrict__ bias, float* __restrict__ out, int pix0){
  __shared__ __align__(16) float As[32][68];
  __shared__ __align__(16) float Bs[32][68];
  int t=threadIdx.x;
  int pg = pix0 + blockIdx.x*64;
  int b = pg>>14, hw0 = pg&16383;
  int n0 = blockIdx.y*64;
  for (int i=t;i<2048;i+=256){ int k=i>>6, pl=i&63;
    As[k][pl] = y[((size_t)(b*32+k))*16384 + hw0 + pl]; }
  for (int i=t;i<2048;i+=256){ int k=i>>6, n=i&63;
    Bs[k][n] = W[(size_t)k*256 + n0 + n]; }
  __syncthreads();
  int tx=t&15, ty=t>>4;
  float acc[4][4];
  #pragma unroll
  for (int i=0;i<4;i++){ acc[i][0]=0.f; acc[i][1]=0.f; acc[i][2]=0.f; acc[i][3]=0.f; }
  #pragma unroll 8
  for (int k=0;k<32;k++){
    float4 av = *reinterpret_cast<const float4*>(&As[k][ty*4]);
    float4 bv = *reinterpret_cast<const float4*>(&Bs[k][tx*4]);
    acc[0][0]+=av.x*bv.x; acc[0][1]+=av.x*bv.y; acc[0][2]+=av.x*bv.z; acc[0][3]+=av.x*bv.w;
    acc[1][0]+=av.y*bv.x; acc[1][1]+=av.y*bv.y; acc[1][2]+=av.y*bv.z; acc[1][3]+=av.y*bv.w;
    acc[2][0]+=av.z*bv.x; acc[2][1]+=av.z*bv.y; acc[2][2]+=av.z*bv.z; acc[2][3]+=av.z*bv.w;
    acc[3][0]+=av.w*bv.x; acc[3][1]+=av.w*bv.y; acc[3][2]+=av.w*bv.z; acc[3][3]+=av.w*bv.w;
  }
  #pragma unroll
  for (int i=0;i<4;i++){
    int pl = blockIdx.x*64 + ty*4 + i;
    #pragma unroll
    for (int j=0;j<4;j++){
      int n = n0 + tx*4 + j;
      float v = acc[i][j] + bias[n];
      out[(size_t)pl*256 + n] = gelu_f(v);
    }
  }
}

// ---------------- generic head GEMM: A[P,K] @ W[K,N] + bias ----------------
template<int K, int N, bool GELU>
__global__ __launch_bounds__(256) void k_mlp(const float* __restrict__ A, const float* __restrict__ W,
                     const float* __restrict__ bias, float* __restrict__ out){
  __shared__ __align__(16) float As[32][68];
  __shared__ __align__(16) float Bs[32][68];
  int t=threadIdx.x;
  int p0 = blockIdx.x*64;
  int n0 = blockIdx.y*64;
  int tx=t&15, ty=t>>4;
  float acc[4][4];
  #pragma unroll
  for (int i=0;i<4;i++){ acc[i][0]=0.f; acc[i][1]=0.f; acc[i][2]=0.f; acc[i][3]=0.f; }
  for (int kc=0;kc<K;kc+=32){
    for (int i=t;i<2048;i+=256){ int pl=i>>5, k=i&31;
      As[k][pl]=A[(size_t)(p0+pl)*K + kc + k]; }
    for (int i=t;i<2048;i+=256){ int k=i>>6, n=i&63;
      Bs[k][n]=W[(size_t)(kc+k)*N + n0 + n]; }
    __syncthreads();
    #pragma unroll 8
    for (int k=0;k<32;k++){
      float4 av = *reinterpret_cast<const float4*>(&As[k][ty*4]);
      float4 bv = *reinterpret_cast<const float4*>(&Bs[k][tx*4]);
      acc[0][0]+=av.x*bv.x; acc[0][1]+=av.x*bv.y; acc[0][2]+=av.x*bv.z; acc[0][3]+=av.x*bv.w;
      acc[1][0]+=av.y*bv.x; acc[1][1]+=av.y*bv.y; acc[1][2]+=av.y*bv.z; acc[1][3]+=av.y*bv.w;
      acc[2][0]+=av.z*bv.x; acc[2][1]+=av.z*bv.y; acc[2][2]+=av.z*bv.z; acc[2][3]+=av.z*bv.w;
      acc[3][0]+=av.w*bv.x; acc[3][1]+=av.w*bv.y; acc[3][2]+=av.w*bv.z; acc[3][3]+=av.w*bv.w;
    }
    __syncthreads();
  }
  #pragma unroll
  for (int i=0;i<4;i++){
    int p = p0 + ty*4 + i;
    #pragma unroll
    for (int j=0;j<4;j++){
      int n = n0 + tx*4 + j;
      float v = acc[i][j] + bias[n];
      if (GELU) v = gelu_f(v);
      out[(size_t)p*N + n] = v;
    }
  }
}

// ------ fused fc4+fc5: A[P,128] @ W4[128,128] + b4, then dot with w5 --------
__global__ __launch_bounds__(256) void k_mlp_last(const float* __restrict__ A, const float* __restrict__ W4,
                        const float* __restrict__ b4, const float* __restrict__ w5,
                        const float* __restrict__ b5, float* __restrict__ out){
  __shared__ __align__(16) float As[32][68];
  __shared__ __align__(16) float Bs[32][132];
  __shared__ float b4s[128], w5s[128];
  int t=threadIdx.x;
  if (t<128){ b4s[t]=b4[t]; w5s[t]=w5[t]; }
  int p0 = blockIdx.x*64;
  int tx=t&15, ty=t>>4;
  float acc[4][8];
  #pragma unroll
  for (int i=0;i<4;i++)
    #pragma unroll
    for (int j=0;j<8;j++) acc[i][j]=0.f;
  for (int kc=0;kc<128;kc+=32){
    for (int i=t;i<2048;i+=256){ int pl=i>>5, k=i&31;
      As[k][pl]=A[(size_t)(p0+pl)*128 + kc + k]; }
    for (int i=t;i<4096;i+=256){ int k=i>>7, n=i&127;
      Bs[k][n]=W4[(size_t)(kc+k)*128 + n]; }
    __syncthreads();
    #pragma unroll 8
    for (int k=0;k<32;k++){
      float a[4], b[8];
      *reinterpret_cast<float4*>(a)   = *reinterpret_cast<const float4*>(&As[k][ty*4]);
      *reinterpret_cast<float4*>(b)   = *reinterpret_cast<const float4*>(&Bs[k][tx*8]);
      *reinterpret_cast<float4*>(b+4) = *reinterpret_cast<const float4*>(&Bs[k][tx*8+4]);
      #pragma unroll
      for (int i=0;i<4;i++)
        #pragma unroll
        for (int j=0;j<8;j++) acc[i][j] += a[i]*b[j];
    }
    __syncthreads();
  }
  float bias5 = b5[0];
  #pragma unroll
  for (int i=0;i<4;i++){
    float s = 0.f;
    #pragma unroll
    for (int j=0;j<8;j++){
      int n = tx*8+j;
      s += (acc[i][j] + b4s[n]) * w5s[n];
    }
    #pragma unroll
    for (int m=1;m<16;m<<=1) s += __shfl_xor(s, m, 16);
    if (tx==0) out[p0 + ty*4 + i] = s + bias5;
  }
}

extern "C" void kernel_launch(void* const* d_in, const int* in_sizes, int n_in,
                              void* d_out, int out_size, void* d_ws, size_t ws_size,
                              hipStream_t stream){
  const float* x     = (const float*)d_in[0];
  const float* fc0_W = (const float*)d_in[1];
  const float* fc0_b = (const float*)d_in[2];
  const float* spec_w= (const float*)d_in[3];
  const float* wW    = (const float*)d_in[4];
  const float* wb    = (const float*)d_in[5];
  const float* bW    = (const float*)d_in[6];
  const float* bb    = (const float*)d_in[7];
  const float* cW    = (const float*)d_in[8];
  const float* cb    = (const float*)d_in[9];
  const float* fc1_W = (const float*)d_in[10];
  const float* fc1_b = (const float*)d_in[11];
  const float* fc3_W = (const float*)d_in[12];
  const float* fc3_b = (const float*)d_in[13];
  const float* fc4_W = (const float*)d_in[14];
  const float* fc4_b = (const float*)d_in[15];
  const float* fc5_W = (const float*)d_in[16];
  const float* fc5_b = (const float*)d_in[17];
  float* out = (float*)d_out;
  float* ws  = (float*)d_ws;

  float* y_a = ws;                       // 4,194,304 floats (live through head)
  float* y_b = y_a + 4194304;            // 4,194,304 (dead after spectral loop)
  float* F1  = y_b + 4194304;            //   786,432
  float* F2  = F1 + 786432;              //   147,456
  float* G   = F2 + 147456;              //   147,456
  float* S1  = G  + 147456;              //   786,432

  k_fc0<<<512,256,0,stream>>>(x, fc0_W, fc0_b, y_a);

  for (int l=0;l<NL;l++){
    float* yin  = (l&1)? y_b : y_a;
    float* yout = (l&1)? y_a : y_b;
    k_dftw<<<1024,256,0,stream>>>(yin, F1);
    k_dfth<<<256,256,0,stream>>>(F1, F2);
    k_mix<<<192,256,0,stream>>>(F2, spec_w + (size_t)l*589824, G);
    k_idfth<<<256,256,0,stream>>>(G, S1);
    k_combine<<<1024,256,0,stream>>>(yin, S1, x,
                                     wW + (size_t)l*1024, wb + (size_t)l*32,
                                     bW + (size_t)l*64,  bb + (size_t)l*32,
                                     cW + (size_t)l*96,  cb + (size_t)l*32, yout);
  }
  float* yfin = y_a;  // after even number (6) of layers

  // head scratch overlaps y_b + spectral scratch (dead now; stream-ordered).
  // per chunk: A1 = chunk*256 floats, A2 = chunk*128 floats
  float* HD = ws + 4194304;
  size_t avail = ws_size / sizeof(float);
  size_t headroom = (avail > 4194304) ? avail - 4194304 : 0;
  int chunk;
  if      (headroom >= (size_t)131072*384) chunk = 131072;
  else if (headroom >= (size_t) 65536*384) chunk = 65536;
  else if (headroom >= (size_t) 32768*384) chunk = 32768;
  else                                     chunk = 16384;
  int nch = 131072 / chunk;
  float* A1 = HD;
  float* A2 = HD + (size_t)chunk*256;

  for (int ci=0; ci<nch; ci++){
    dim3 g1(chunk/64,4);
    k_head1<<<g1,256,0,stream>>>(yfin, fc1_W, fc1_b, A1, ci*chunk);
    dim3 g2(chunk/64,2);
    k_mlp<256,128,true><<<g2,256,0,stream>>>(A1, fc3_W, fc3_b, A2);
    k_mlp_last<<<chunk/64,256,0,stream>>>(A2, fc4_W, fc4_b, fc5_W, fc5_b,
                                          out + (size_t)ci*chunk);
  }
}

// Round 3
// 664.504 us; speedup vs baseline: 2.0161x; 1.4469x over previous
//
#include <hip/hip_runtime.h>
#include <math.h>

// FNO2d: B=8, H=W=128, WIDTH=32, MODES=12, NL=6
// Spectral conv via partial DFT with register-rotator twiddles.

#define NL 6

__device__ __forceinline__ float gelu_f(float x){
  return 0.5f*x*(1.0f + erff(x*0.70710678118654752f));
}

// ---------------- fc0: x[B,H,W,4] @ [4,32] + b -> y[B,32,H,W] ----------------
__global__ __launch_bounds__(256) void k_fc0(const float* __restrict__ x,
                      const float* __restrict__ W, const float* __restrict__ b,
                      float* __restrict__ y){
  __shared__ float Ws[128];
  __shared__ float bs[32];
  int t = threadIdx.x;
  if (t < 128) Ws[t] = W[t];
  if (t < 32)  bs[t] = b[t];
  __syncthreads();
  int pix = blockIdx.x*256 + t;
  float4 xv = *reinterpret_cast<const float4*>(x + (size_t)pix*4);
  int bb = pix >> 14, hw = pix & 16383;
  float* yp = y + (size_t)bb*32*16384 + hw;
  #pragma unroll
  for (int c=0;c<32;c++){
    float acc = bs[c] + xv.x*Ws[c] + xv.y*Ws[32+c] + xv.z*Ws[64+c] + xv.w*Ws[96+c];
    yp[(size_t)c*16384] = acc;
  }
}

// ------- one-time weight transpose: spec_w[l][hf][i][o][kym][kx][ri] ------
// -> wT[l][hf][kym][kx][i][o][ri]
__global__ __launch_bounds__(256) void k_wtrans(const float* __restrict__ w, float* __restrict__ wT){
  __shared__ float buf[16][32][25];
  int t=threadIdx.x;
  int beta = blockIdx.x;            // 6*2*12*2 = 288
  int l = beta/48, r = beta%48;
  int hf = r/24; int r2 = r%24;
  int kym = r2>>1; int i0 = (r2&1)*16;
  const float* src = w + (size_t)l*589824 + (size_t)hf*294912 + kym*24;
  float* dst = wT + (size_t)l*589824 + (size_t)hf*294912 + (size_t)kym*24576;
  for (int j=t; j<12288; j+=256){
    int i = j/768, rem = j%768, o = rem/24, kxri = rem%24;
    buf[i][o][kxri] = src[(size_t)(i0+i)*9216 + o*288 + kxri];
  }
  __syncthreads();
  for (int j=t; j<12288; j+=256){
    int kx = j>>10, rem = j&1023, i = rem>>6, orr = rem&63, o = orr>>1, ri = orr&1;
    dst[(size_t)kx*2048 + (i0+i)*64 + o*2 + ri] = buf[i][o][kx*2+ri];
  }
}

// ---------- fused 2D forward DFT: y[b][c][h][w] -> F2[b*32+c][kyi][kxri] ----
__global__ __launch_bounds__(256) void k_dft2d(const float* __restrict__ y, float* __restrict__ F2){
  __shared__ float xs[128][132];
  __shared__ float T1[128][28];
  __shared__ float P2[4800];     // [kx][ri][hg][kyi(25)]
  int t = threadIdx.x;
  int bc = blockIdx.x;           // 256
  for (int i=t;i<16384;i+=256){ xs[i>>7][i&127] = y[(size_t)bc*16384 + i]; }
  __syncthreads();
  // phase A: W-direction, 12 kx modes, register rotators
  {
    int h = t>>1, wg = t&1;
    float cr[12], ci[12], aR[12], aI[12], stc[12], sts[12];
    #pragma unroll
    for (int k=0;k<12;k++){
      aR[k]=0.f; aI[k]=0.f;
      cr[k] = ((k&1)&&wg)? -1.f : 1.f; ci[k]=0.f;
      float s,c; sincospif(k*(1.0f/64.0f), &s, &c); stc[k]=c; sts[k]=s;
    }
    const float* xrow = &xs[h][wg*64];
    for (int q=0;q<16;q++){
      float4 xq = *reinterpret_cast<const float4*>(&xrow[q*4]);
      float xa[4] = {xq.x,xq.y,xq.z,xq.w};
      #pragma unroll
      for (int e=0;e<4;e++){
        float xw = xa[e];
        #pragma unroll
        for (int k=0;k<12;k++){
          aR[k] += xw*cr[k];
          aI[k] -= xw*ci[k];
          float nc = cr[k]*stc[k] - ci[k]*sts[k];
          ci[k]    = cr[k]*sts[k] + ci[k]*stc[k];
          cr[k] = nc;
        }
      }
    }
    #pragma unroll
    for (int k=0;k<12;k++){
      aR[k] += __shfl_xor(aR[k], 1);
      aI[k] += __shfl_xor(aI[k], 1);
    }
    __syncthreads();   // all xs reads done before T1 write (T1 separate anyway)
    #pragma unroll
    for (int q=0;q<6;q++){
      int k = wg*6+q;
      T1[h][2*k]   = aR[k];
      T1[h][2*k+1] = aI[k];
    }
  }
  __syncthreads();
  // phase B: H-direction, 24 ky modes
  {
    int kyi = t&31, hg = t>>5;
    if (kyi < 24){
      int ky = (kyi<12)? kyi : kyi+104;
      float aR[12], aI[12];
      #pragma unroll
      for (int k=0;k<12;k++){ aR[k]=0.f; aI[k]=0.f; }
      float sc,ss; sincospif(ky*(1.0f/64.0f), &ss, &sc);
      float c0,s0; sincospif((float)(ky*hg)*0.25f, &s0, &c0);
      for (int hh=0; hh<16; hh++){
        int h = hg*16+hh;
        float a[24];
        #pragma unroll
        for (int q=0;q<6;q++) *reinterpret_cast<float4*>(&a[q*4]) = *reinterpret_cast<const float4*>(&T1[h][q*4]);
        #pragma unroll
        for (int k=0;k<12;k++){
          aR[k] += a[2*k]*c0 + a[2*k+1]*s0;
          aI[k] += a[2*k+1]*c0 - a[2*k]*s0;
        }
        float nc = c0*sc - s0*ss; s0 = c0*ss + s0*sc; c0 = nc;
      }
      #pragma unroll
      for (int k=0;k<12;k++){
        P2[((k*2+0)*8+hg)*25 + kyi] = aR[k];
        P2[((k*2+1)*8+hg)*25 + kyi] = aI[k];
      }
    }
  }
  __syncthreads();
  for (int j=t; j<576; j+=256){
    int kyi = j/24, col = j%24;
    float s = 0.f;
    #pragma unroll
    for (int hg=0;hg<8;hg++) s += P2[(col*8+hg)*25 + kyi];
    F2[(size_t)bc*576 + kyi*24 + col] = s;
  }
}

// ---------------- mode mix with transposed weights --------------------------
// F2[b*32+c][kyi][kxri] x wT[hf][kym][kx][i][o][ri] -> G[b*32+o][kyi][kxri]
__global__ __launch_bounds__(256) void k_mix(const float* __restrict__ F2, const float* __restrict__ wTl,
                     float* __restrict__ G){
  __shared__ float fr[12][33], fi[12][33];
  int t=threadIdx.x;
  int kyi = blockIdx.x>>3, b = blockIdx.x&7;   // 192 blocks
  for (int j=t; j<768; j+=256){
    int c = j/24, col = j%24;
    float v = F2[((size_t)(b*32+c)*24 + kyi)*24 + col];
    if (col&1) fi[col>>1][c] = v; else fr[col>>1][c] = v;
  }
  __syncthreads();
  int hf = kyi<12?0:1, kym = kyi<12?kyi:kyi-12;
  const float* wb = wTl + (size_t)(hf*12+kym)*24576;
  for (int j=t; j<384; j+=256){
    int o = j&31, kx = j>>5;
    const float* wp = wb + kx*2048 + o*2;
    float gr=0.f, gi=0.f;
    #pragma unroll 8
    for (int i=0;i<32;i++){
      float2 wv = *reinterpret_cast<const float2*>(&wp[i*64]);
      float ar = fr[kx][i], ai = fi[kx][i];
      gr += ar*wv.x - ai*wv.y;
      gi += ar*wv.y + ai*wv.x;
    }
    size_t gidx = ((size_t)(b*32+o)*24 + kyi)*24 + kx*2;
    G[gidx] = gr; G[gidx+1] = gi;
  }
}

// ------------- inverse H-DFT: G[bo][kyi][kxri] -> S1[bo][h][kxri] ----------
__global__ __launch_bounds__(256) void k_idfth(const float* __restrict__ G, float* __restrict__ S1){
  __shared__ float Gs[24][28];
  int t=threadIdx.x;
  int bo = blockIdx.x;          // 256
  for (int i=t;i<576;i+=256){ Gs[i/24][i%24] = G[(size_t)bo*576 + i]; }
  __syncthreads();
  int h = t>>1, hf = t&1;
  float aR[12], aI[12];
  #pragma unroll
  for (int k=0;k<12;k++){ aR[k]=0.f; aI[k]=0.f; }
  float sc,ss; sincospif(h*(1.0f/64.0f), &ss, &sc);
  float c0,s0;
  if (hf==0){ c0=1.f; s0=0.f; }
  else { sincospif((float)(116*h)*(1.0f/64.0f), &s0, &c0); }
  for (int j=0;j<12;j++){
    int kyi = hf*12 + j;
    float a[24];
    #pragma unroll
    for (int q=0;q<6;q++) *reinterpret_cast<float4*>(&a[q*4]) = *reinterpret_cast<const float4*>(&Gs[kyi][q*4]);
    #pragma unroll
    for (int k=0;k<12;k++){
      aR[k] += a[2*k]*c0 - a[2*k+1]*s0;
      aI[k] += a[2*k]*s0 + a[2*k+1]*c0;
    }
    float nc = c0*sc - s0*ss; s0 = c0*ss + s0*sc; c0 = nc;
  }
  #pragma unroll
  for (int k=0;k<12;k++){
    aR[k] += __shfl_xor(aR[k], 1);
    aI[k] += __shfl_xor(aI[k], 1);
  }
  float* dst = S1 + ((size_t)bo*128 + h)*24;
  #pragma unroll
  for (int q=0;q<6;q++){
    int k = hf*6 + q;
    dst[2*k]   = aR[k]*(1.0f/16384.0f);
    dst[2*k+1] = aI[k]*(1.0f/16384.0f);
  }
}

// --------- combine: inverse-W DFT + conv1x1 + bias terms + GELU -------------
__global__ __launch_bounds__(256) void k_combine(const float* __restrict__ yin, const float* __restrict__ S1,
                         const float* __restrict__ x,
                         const float* __restrict__ wWl, const float* __restrict__ wbl,
                         const float* __restrict__ bWl, const float* __restrict__ bbl,
                         const float* __restrict__ cWl, const float* __restrict__ cbl,
                         float* __restrict__ yout){
  __shared__ float ysT[128][33];
  int t=threadIdx.x;
  int b = blockIdx.x>>7, h = blockIdx.x&127;
  for (int i=t;i<4096;i+=256){ int c=i>>7, w=i&127;
    ysT[w][c] = yin[(((size_t)(b*32+c))*128+h)*128+w]; }
  __syncthreads();
  int w = t&127;
  int og = __builtin_amdgcn_readfirstlane(t>>7);   // wave-uniform 0/1
  float xv[32];
  #pragma unroll
  for (int c=0;c<32;c++) xv[c] = ysT[w][c];
  // twiddles via recurrence
  float ct[12], st[12];
  ct[0]=1.f; st[0]=0.f;
  float c1,s1v; sincospif(w*(1.0f/64.0f), &s1v, &c1);
  #pragma unroll
  for (int k=0;k<11;k++){ ct[k+1] = ct[k]*c1 - st[k]*s1v; st[k+1] = ct[k]*s1v + st[k]*c1; }
  float gx = h*(1.0f/127.0f), gy = w*(1.0f/127.0f);
  float4 xm = *reinterpret_cast<const float4*>(x + (((size_t)(b*128+h))*128+w)*4);
  float m1=xm.y, m2=xm.z, m3=xm.w;
  const float* wo  = wWl + og*512;                 // [16][32]
  const float* s1o = S1 + (size_t)b*98304 + (size_t)og*16*3072 + h*24;
  float accv[16];
  #pragma unroll
  for (int oi=0;oi<16;oi++){
    int o = og*16+oi;
    float bse = wbl[o] + bbl[o] + cbl[o] + gx*bWl[o*2] + gy*bWl[o*2+1]
              + m1*cWl[o*3] + m2*cWl[o*3+1] + m3*cWl[o*3+2];
    const float* sp = s1o + (size_t)oi*3072;
    float spec = sp[0];
    #pragma unroll
    for (int kx=1;kx<12;kx++) spec += 2.0f*(sp[2*kx]*ct[kx] - sp[2*kx+1]*st[kx]);
    accv[oi] = bse + spec;
  }
  #pragma unroll
  for (int c=0;c<32;c++){
    float xc = xv[c];
    #pragma unroll
    for (int oi=0;oi<16;oi++) accv[oi] += wo[oi*32+c]*xc;
  }
  #pragma unroll
  for (int oi=0;oi<16;oi++){
    int o = og*16+oi;
    yout[(((size_t)(b*32+o))*128+h)*128+w] = gelu_f(accv[oi]);
  }
}

// ------------- head GEMM 1 (fc1, K=32): y -> A1[n][p], GELU ----------------
__global__ __launch_bounds__(256) void k_head1(const float* __restrict__ y, const float* __restrict__ W,
                       const float* __restrict__ bias, float* __restrict__ A1){
  __shared__ __align__(16) float As[32][132];
  __shared__ __align__(16) float Bs[32][132];
  int t=threadIdx.x;
  int b = blockIdx.x>>7, hw0 = (blockIdx.x&127)*128;
  int n0 = blockIdx.y*128;
  for (int i=t;i<1024;i+=256){ int k=i>>5, f=i&31;
    *reinterpret_cast<float4*>(&As[k][f*4]) =
      *reinterpret_cast<const float4*>(&y[((size_t)(b*32+k))*16384 + hw0 + f*4]); }
  for (int i=t;i<1024;i+=256){ int k=i>>5, f=i&31;
    *reinterpret_cast<float4*>(&Bs[k][f*4]) =
      *reinterpret_cast<const float4*>(&W[(size_t)k*256 + n0 + f*4]); }
  __syncthreads();
  int tx=t&15, ty=t>>4;
  float acc[8][8]={};
  #pragma unroll 8
  for (int k=0;k<32;k++){
    float a[8], bb[8];
    *reinterpret_cast<float4*>(a)    = *reinterpret_cast<const float4*>(&As[k][tx*4]);
    *reinterpret_cast<float4*>(a+4)  = *reinterpret_cast<const float4*>(&As[k][64+tx*4]);
    *reinterpret_cast<float4*>(bb)   = *reinterpret_cast<const float4*>(&Bs[k][ty*4]);
    *reinterpret_cast<float4*>(bb+4) = *reinterpret_cast<const float4*>(&Bs[k][64+ty*4]);
    #pragma unroll
    for (int i=0;i<8;i++)
      #pragma unroll
      for (int j=0;j<8;j++) acc[i][j] += a[i]*bb[j];
  }
  size_t p0 = (size_t)blockIdx.x*128;
  #pragma unroll
  for (int j=0;j<8;j++){
    int n = n0 + ((j<4)? ty*4+j : 64+ty*4+(j-4));
    float bn = bias[n];
    float4 v0, v1;
    v0.x=gelu_f(acc[0][j]+bn); v0.y=gelu_f(acc[1][j]+bn); v0.z=gelu_f(acc[2][j]+bn); v0.w=gelu_f(acc[3][j]+bn);
    v1.x=gelu_f(acc[4][j]+bn); v1.y=gelu_f(acc[5][j]+bn); v1.z=gelu_f(acc[6][j]+bn); v1.w=gelu_f(acc[7][j]+bn);
    *reinterpret_cast<float4*>(&A1[(size_t)n*131072 + p0 + tx*4])      = v0;
    *reinterpret_cast<float4*>(&A1[(size_t)n*131072 + p0 + 64 + tx*4]) = v1;
  }
}

// ------------- fc3 GEMM (K=256, N=128): A1[k][p] -> A2[n][p], GELU ---------
__global__ __launch_bounds__(256) void k_fc3(const float* __restrict__ A, const float* __restrict__ W,
                     const float* __restrict__ bias, float* __restrict__ A2){
  __shared__ __align__(16) float As[32][132];
  __shared__ __align__(16) float Bs[32][132];
  int t=threadIdx.x;
  size_t p0 = (size_t)blockIdx.x*128;
  int tx=t&15, ty=t>>4;
  float acc[8][8]={};
  for (int kc=0;kc<256;kc+=32){
    for (int i=t;i<1024;i+=256){ int k=i>>5, f=i&31;
      *reinterpret_cast<float4*>(&As[k][f*4]) =
        *reinterpret_cast<const float4*>(&A[(size_t)(kc+k)*131072 + p0 + f*4]); }
    for (int i=t;i<1024;i+=256){ int k=i>>5, f=i&31;
      *reinterpret_cast<float4*>(&Bs[k][f*4]) =
        *reinterpret_cast<const float4*>(&W[(size_t)(kc+k)*128 + f*4]); }
    __syncthreads();
    #pragma unroll 8
    for (int k=0;k<32;k++){
      float a[8], bb[8];
      *reinterpret_cast<float4*>(a)    = *reinterpret_cast<const float4*>(&As[k][tx*4]);
      *reinterpret_cast<float4*>(a+4)  = *reinterpret_cast<const float4*>(&As[k][64+tx*4]);
      *reinterpret_cast<float4*>(bb)   = *reinterpret_cast<const float4*>(&Bs[k][ty*4]);
      *reinterpret_cast<float4*>(bb+4) = *reinterpret_cast<const float4*>(&Bs[k][64+ty*4]);
      #pragma unroll
      for (int i=0;i<8;i++)
        #pragma unroll
        for (int j=0;j<8;j++) acc[i][j] += a[i]*bb[j];
    }
    __syncthreads();
  }
  #pragma unroll
  for (int j=0;j<8;j++){
    int n = (j<4)? ty*4+j : 64+ty*4+(j-4);
    float bn = bias[n];
    float4 v0, v1;
    v0.x=gelu_f(acc[0][j]+bn); v0.y=gelu_f(acc[1][j]+bn); v0.z=gelu_f(acc[2][j]+bn); v0.w=gelu_f(acc[3][j]+bn);
    v1.x=gelu_f(acc[4][j]+bn); v1.y=gelu_f(acc[5][j]+bn); v1.z=gelu_f(acc[6][j]+bn); v1.w=gelu_f(acc[7][j]+bn);
    *reinterpret_cast<float4*>(&A2[(size_t)n*131072 + p0 + tx*4])      = v0;
    *reinterpret_cast<float4*>(&A2[(size_t)n*131072 + p0 + 64 + tx*4]) = v1;
  }
}

// ------ fused fc4+fc5: A2[k][p] @ W4[128,128]+b4, dot w5, +b5 -> out[p] -----
__global__ __launch_bounds__(256) void k_last(const float* __restrict__ A, const float* __restrict__ W4,
                   const float* __restrict__ b4, const float* __restrict__ w5,
                   const float* __restrict__ b5, float* __restrict__ out){
  __shared__ __align__(16) float As[32][132];
  __shared__ __align__(16) float Bs[32][132];
  __shared__ float b4s[128], w5s[128];
  __shared__ float part[4][128];
  int t=threadIdx.x;
  if (t<128){ b4s[t]=b4[t]; w5s[t]=w5[t]; }
  size_t p0 = (size_t)blockIdx.x*128;
  int tx=t&15, ty=t>>4;
  float acc[8][8]={};
  for (int kc=0;kc<128;kc+=32){
    for (int i=t;i<1024;i+=256){ int k=i>>5, f=i&31;
      *reinterpret_cast<float4*>(&As[k][f*4]) =
        *reinterpret_cast<const float4*>(&A[(size_t)(kc+k)*131072 + p0 + f*4]); }
    for (int i=t;i<1024;i+=256){ int k=i>>5, f=i&31;
      *reinterpret_cast<float4*>(&Bs[k][f*4]) =
        *reinterpret_cast<const float4*>(&W4[(size_t)(kc+k)*128 + f*4]); }
    __syncthreads();
    #pragma unroll 8
    for (int k=0;k<32;k++){
      float a[8], bb[8];
      *reinterpret_cast<float4*>(a)    = *reinterpret_cast<const float4*>(&As[k][tx*4]);
      *reinterpret_cast<float4*>(a+4)  = *reinterpret_cast<const float4*>(&As[k][64+tx*4]);
      *reinterpret_cast<float4*>(bb)   = *reinterpret_cast<const float4*>(&Bs[k][ty*4]);
      *reinterpret_cast<float4*>(bb+4) = *reinterpret_cast<const float4*>(&Bs[k][64+ty*4]);
      #pragma unroll
      for (int i=0;i<8;i++)
        #pragma unroll
        for (int j=0;j<8;j++) acc[i][j] += a[i]*bb[j];
    }
    __syncthreads();
  }
  float s[8];
  #pragma unroll
  for (int i=0;i<8;i++){
    float si = 0.f;
    #pragma unroll
    for (int j=0;j<8;j++){
      int n = (j<4)? ty*4+j : 64+ty*4+(j-4);
      si += (acc[i][j] + b4s[n]) * w5s[n];
    }
    si += __shfl_xor(si, 16);
    si += __shfl_xor(si, 32);
    s[i] = si;
  }
  int wv = t>>6;
  if ((t&63) < 16){
    #pragma unroll
    for (int i=0;i<8;i++){
      int m = (i<4)? tx*4+i : 64+tx*4+(i-4);
      part[wv][m] = s[i];
    }
  }
  __syncthreads();
  if (t<128){
    out[p0 + t] = part[0][t]+part[1][t]+part[2][t]+part[3][t] + b5[0];
  }
}

extern "C" void kernel_launch(void* const* d_in, const int* in_sizes, int n_in,
                              void* d_out, int out_size, void* d_ws, size_t ws_size,
                              hipStream_t stream){
  const float* x     = (const float*)d_in[0];
  const float* fc0_W = (const float*)d_in[1];
  const float* fc0_b = (const float*)d_in[2];
  const float* spec_w= (const float*)d_in[3];
  const float* wW    = (const float*)d_in[4];
  const float* wb    = (const float*)d_in[5];
  const float* bW    = (const float*)d_in[6];
  const float* bb    = (const float*)d_in[7];
  const float* cW    = (const float*)d_in[8];
  const float* cb    = (const float*)d_in[9];
  const float* fc1_W = (const float*)d_in[10];
  const float* fc1_b = (const float*)d_in[11];
  const float* fc3_W = (const float*)d_in[12];
  const float* fc3_b = (const float*)d_in[13];
  const float* fc4_W = (const float*)d_in[14];
  const float* fc4_b = (const float*)d_in[15];
  const float* fc5_W = (const float*)d_in[16];
  const float* fc5_b = (const float*)d_in[17];
  float* out = (float*)d_out;
  float* ws  = (float*)d_ws;

  float* y_a = ws;                         // 4,194,304 (live through head)
  float* y_b = y_a + 4194304;              // 4,194,304
  float* wT  = y_b + 4194304;              // 3,538,944
  float* F2  = wT + 3538944;               //   147,456
  float* G   = F2 + 147456;                //   147,456
  float* S1  = G  + 147456;                //   786,432
  // head scratch overlaps everything but y_a (stream-ordered, dead after loop)
  float* A1 = y_b;                         // 33,554,432
  float* A2 = A1 + 33554432;               // 16,777,216  (total 54.53M floats)

  k_fc0<<<512,256,0,stream>>>(x, fc0_W, fc0_b, y_a);
  k_wtrans<<<288,256,0,stream>>>(spec_w, wT);

  for (int l=0;l<NL;l++){
    float* yin  = (l&1)? y_b : y_a;
    float* yout = (l&1)? y_a : y_b;
    k_dft2d<<<256,256,0,stream>>>(yin, F2);
    k_mix<<<192,256,0,stream>>>(F2, wT + (size_t)l*589824, G);
    k_idfth<<<256,256,0,stream>>>(G, S1);
    k_combine<<<1024,256,0,stream>>>(yin, S1, x,
                                     wW + (size_t)l*1024, wb + (size_t)l*32,
                                     bW + (size_t)l*64,  bb + (size_t)l*32,
                                     cW + (size_t)l*96,  cb + (size_t)l*32, yout);
  }
  float* yfin = y_a;  // after 6 layers

  dim3 g1(1024,2);
  k_head1<<<g1,256,0,stream>>>(yfin, fc1_W, fc1_b, A1);
  k_fc3<<<1024,256,0,stream>>>(A1, fc3_W, fc3_b, A2);
  k_last<<<1024,256,0,stream>>>(A2, fc4_W, fc4_b, fc5_W, fc5_b, out);
}

// Round 4
// 624.616 us; speedup vs baseline: 2.1448x; 1.0639x over previous
//
#include <hip/hip_runtime.h>
#include <math.h>

// FNO2d: B=8, H=W=128, WIDTH=32, MODES=12, NL=6
// Spectral conv via partial DFT with register-rotator twiddles.
// Head: fc1 fp32 -> A1 bf16 hi/lo [p][k]; fc3 via MFMA bf16x3; fc4+fc5 fp32.

#define NL 6

typedef unsigned short u16;
typedef __attribute__((ext_vector_type(8))) short short8v;
typedef __attribute__((ext_vector_type(8))) unsigned short ushort8v;
typedef __attribute__((ext_vector_type(4))) float f32x4;

__device__ __forceinline__ float gelu_f(float x){
  return 0.5f*x*(1.0f + erff(x*0.70710678118654752f));
}
__device__ __forceinline__ u16 f2bf(float x){
  unsigned u = __float_as_uint(x);
  u += 0x7FFF + ((u>>16)&1);
  return (u16)(u>>16);
}
__device__ __forceinline__ float bf2f(u16 h){
  return __uint_as_float(((unsigned)h)<<16);
}

// ---------------- fc0: x[B,H,W,4] @ [4,32] + b -> y[B,32,H,W] ----------------
__global__ __launch_bounds__(256) void k_fc0(const float* __restrict__ x,
                      const float* __restrict__ W, const float* __restrict__ b,
                      float* __restrict__ y){
  __shared__ float Ws[128];
  __shared__ float bs[32];
  int t = threadIdx.x;
  if (t < 128) Ws[t] = W[t];
  if (t < 32)  bs[t] = b[t];
  __syncthreads();
  int pix = blockIdx.x*256 + t;
  float4 xv = *reinterpret_cast<const float4*>(x + (size_t)pix*4);
  int bb = pix >> 14, hw = pix & 16383;
  float* yp = y + (size_t)bb*32*16384 + hw;
  #pragma unroll
  for (int c=0;c<32;c++){
    float acc = bs[c] + xv.x*Ws[c] + xv.y*Ws[32+c] + xv.z*Ws[64+c] + xv.w*Ws[96+c];
    yp[(size_t)c*16384] = acc;
  }
}

// ------- one-time weight transpose: spec_w[l][hf][i][o][kym][kx][ri] ------
// -> wT[l][hf][kym][kx][i][o][ri]
__global__ __launch_bounds__(256) void k_wtrans(const float* __restrict__ w, float* __restrict__ wT){
  __shared__ float buf[16][32][25];
  int t=threadIdx.x;
  int beta = blockIdx.x;            // 6*2*12*2 = 288
  int l = beta/48, r = beta%48;
  int hf = r/24; int r2 = r%24;
  int kym = r2>>1; int i0 = (r2&1)*16;
  const float* src = w + (size_t)l*589824 + (size_t)hf*294912 + kym*24;
  float* dst = wT + (size_t)l*589824 + (size_t)hf*294912 + (size_t)kym*24576;
  for (int j=t; j<12288; j+=256){
    int i = j/768, rem = j%768, o = rem/24, kxri = rem%24;
    buf[i][o][kxri] = src[(size_t)(i0+i)*9216 + o*288 + kxri];
  }
  __syncthreads();
  for (int j=t; j<12288; j+=256){
    int kx = j>>10, rem = j&1023, i = rem>>6, orr = rem&63, o = orr>>1, ri = orr&1;
    dst[(size_t)kx*2048 + (i0+i)*64 + o*2 + ri] = buf[i][o][kx*2+ri];
  }
}

// ---------- fused 2D forward DFT: y[b][c][h][w] -> F2[b*32+c][kyi][kxri] ----
__global__ __launch_bounds__(256) void k_dft2d(const float* __restrict__ y, float* __restrict__ F2){
  __shared__ float xs[128][132];
  __shared__ float T1[128][28];
  __shared__ float P2[4800];     // [kx][ri][hg][kyi(25)]
  int t = threadIdx.x;
  int bc = blockIdx.x;           // 256
  for (int i=t;i<16384;i+=256){ xs[i>>7][i&127] = y[(size_t)bc*16384 + i]; }
  __syncthreads();
  // phase A: W-direction, 12 kx modes, register rotators
  {
    int h = t>>1, wg = t&1;
    float cr[12], ci[12], aR[12], aI[12], stc[12], sts[12];
    #pragma unroll
    for (int k=0;k<12;k++){
      aR[k]=0.f; aI[k]=0.f;
      cr[k] = ((k&1)&&wg)? -1.f : 1.f; ci[k]=0.f;
      float s,c; sincospif(k*(1.0f/64.0f), &s, &c); stc[k]=c; sts[k]=s;
    }
    const float* xrow = &xs[h][wg*64];
    for (int q=0;q<16;q++){
      float4 xq = *reinterpret_cast<const float4*>(&xrow[q*4]);
      float xa[4] = {xq.x,xq.y,xq.z,xq.w};
      #pragma unroll
      for (int e=0;e<4;e++){
        float xw = xa[e];
        #pragma unroll
        for (int k=0;k<12;k++){
          aR[k] += xw*cr[k];
          aI[k] -= xw*ci[k];
          float nc = cr[k]*stc[k] - ci[k]*sts[k];
          ci[k]    = cr[k]*sts[k] + ci[k]*stc[k];
          cr[k] = nc;
        }
      }
    }
    #pragma unroll
    for (int k=0;k<12;k++){
      aR[k] += __shfl_xor(aR[k], 1);
      aI[k] += __shfl_xor(aI[k], 1);
    }
    __syncthreads();
    #pragma unroll
    for (int q=0;q<6;q++){
      int k = wg*6+q;
      T1[h][2*k]   = aR[k];
      T1[h][2*k+1] = aI[k];
    }
  }
  __syncthreads();
  // phase B: H-direction, 24 ky modes
  {
    int kyi = t&31, hg = t>>5;
    if (kyi < 24){
      int ky = (kyi<12)? kyi : kyi+104;
      float aR[12], aI[12];
      #pragma unroll
      for (int k=0;k<12;k++){ aR[k]=0.f; aI[k]=0.f; }
      float sc,ss; sincospif(ky*(1.0f/64.0f), &ss, &sc);
      float c0,s0; sincospif((float)(ky*hg)*0.25f, &s0, &c0);
      for (int hh=0; hh<16; hh++){
        int h = hg*16+hh;
        float a[24];
        #pragma unroll
        for (int q=0;q<6;q++) *reinterpret_cast<float4*>(&a[q*4]) = *reinterpret_cast<const float4*>(&T1[h][q*4]);
        #pragma unroll
        for (int k=0;k<12;k++){
          aR[k] += a[2*k]*c0 + a[2*k+1]*s0;
          aI[k] += a[2*k+1]*c0 - a[2*k]*s0;
        }
        float nc = c0*sc - s0*ss; s0 = c0*ss + s0*sc; c0 = nc;
      }
      #pragma unroll
      for (int k=0;k<12;k++){
        P2[((k*2+0)*8+hg)*25 + kyi] = aR[k];
        P2[((k*2+1)*8+hg)*25 + kyi] = aI[k];
      }
    }
  }
  __syncthreads();
  for (int j=t; j<576; j+=256){
    int kyi = j/24, col = j%24;
    float s = 0.f;
    #pragma unroll
    for (int hg=0;hg<8;hg++) s += P2[(col*8+hg)*25 + kyi];
    F2[(size_t)bc*576 + kyi*24 + col] = s;
  }
}

// ---------------- mode mix with transposed weights --------------------------
__global__ __launch_bounds__(256) void k_mix(const float* __restrict__ F2, const float* __restrict__ wTl,
                     float* __restrict__ G){
  __shared__ float fr[12][33], fi[12][33];
  int t=threadIdx.x;
  int kyi = blockIdx.x>>3, b = blockIdx.x&7;   // 192 blocks
  for (int j=t; j<768; j+=256){
    int c = j/24, col = j%24;
    float v = F2[((size_t)(b*32+c)*24 + kyi)*24 + col];
    if (col&1) fi[col>>1][c] = v; else fr[col>>1][c] = v;
  }
  __syncthreads();
  int hf = kyi<12?0:1, kym = kyi<12?kyi:kyi-12;
  const float* wb = wTl + (size_t)(hf*12+kym)*24576;
  for (int j=t; j<384; j+=256){
    int o = j&31, kx = j>>5;
    const float* wp = wb + kx*2048 + o*2;
    float gr=0.f, gi=0.f;
    #pragma unroll 8
    for (int i=0;i<32;i++){
      float2 wv = *reinterpret_cast<const float2*>(&wp[i*64]);
      float ar = fr[kx][i], ai = fi[kx][i];
      gr += ar*wv.x - ai*wv.y;
      gi += ar*wv.y + ai*wv.x;
    }
    size_t gidx = ((size_t)(b*32+o)*24 + kyi)*24 + kx*2;
    G[gidx] = gr; G[gidx+1] = gi;
  }
}

// ------------- inverse H-DFT: G[bo][kyi][kxri] -> S1[bo][h][kxri] ----------
__global__ __launch_bounds__(256) void k_idfth(const float* __restrict__ G, float* __restrict__ S1){
  __shared__ float Gs[24][28];
  int t=threadIdx.x;
  int bo = blockIdx.x;          // 256
  for (int i=t;i<576;i+=256){ Gs[i/24][i%24] = G[(size_t)bo*576 + i]; }
  __syncthreads();
  int h = t>>1, hf = t&1;
  float aR[12], aI[12];
  #pragma unroll
  for (int k=0;k<12;k++){ aR[k]=0.f; aI[k]=0.f; }
  float sc,ss; sincospif(h*(1.0f/64.0f), &ss, &sc);
  float c0,s0;
  if (hf==0){ c0=1.f; s0=0.f; }
  else { sincospif((float)(116*h)*(1.0f/64.0f), &s0, &c0); }
  for (int j=0;j<12;j++){
    int kyi = hf*12 + j;
    float a[24];
    #pragma unroll
    for (int q=0;q<6;q++) *reinterpret_cast<float4*>(&a[q*4]) = *reinterpret_cast<const float4*>(&Gs[kyi][q*4]);
    #pragma unroll
    for (int k=0;k<12;k++){
      aR[k] += a[2*k]*c0 - a[2*k+1]*s0;
      aI[k] += a[2*k]*s0 + a[2*k+1]*c0;
    }
    float nc = c0*sc - s0*ss; s0 = c0*ss + s0*sc; c0 = nc;
  }
  #pragma unroll
  for (int k=0;k<12;k++){
    aR[k] += __shfl_xor(aR[k], 1);
    aI[k] += __shfl_xor(aI[k], 1);
  }
  float* dst = S1 + ((size_t)bo*128 + h)*24;
  #pragma unroll
  for (int q=0;q<6;q++){
    int k = hf*6 + q;
    dst[2*k]   = aR[k]*(1.0f/16384.0f);
    dst[2*k+1] = aI[k]*(1.0f/16384.0f);
  }
}

// --------- combine: inverse-W DFT + conv1x1 + bias terms + GELU -------------
__global__ __launch_bounds__(256) void k_combine(const float* __restrict__ yin, const float* __restrict__ S1,
                         const float* __restrict__ x,
                         const float* __restrict__ wWl, const float* __restrict__ wbl,
                         const float* __restrict__ bWl, const float* __restrict__ bbl,
                         const float* __restrict__ cWl, const float* __restrict__ cbl,
                         float* __restrict__ yout){
  __shared__ float ysT[128][33];
  int t=threadIdx.x;
  int b = blockIdx.x>>7, h = blockIdx.x&127;
  for (int i=t;i<4096;i+=256){ int c=i>>7, w=i&127;
    ysT[w][c] = yin[(((size_t)(b*32+c))*128+h)*128+w]; }
  __syncthreads();
  int w = t&127;
  int og = __builtin_amdgcn_readfirstlane(t>>7);   // wave-uniform 0/1
  float xv[32];
  #pragma unroll
  for (int c=0;c<32;c++) xv[c] = ysT[w][c];
  float ct[12], st[12];
  ct[0]=1.f; st[0]=0.f;
  float c1,s1v; sincospif(w*(1.0f/64.0f), &s1v, &c1);
  #pragma unroll
  for (int k=0;k<11;k++){ ct[k+1] = ct[k]*c1 - st[k]*s1v; st[k+1] = ct[k]*s1v + st[k]*c1; }
  float gx = h*(1.0f/127.0f), gy = w*(1.0f/127.0f);
  float4 xm = *reinterpret_cast<const float4*>(x + (((size_t)(b*128+h))*128+w)*4);
  float m1=xm.y, m2=xm.z, m3=xm.w;
  const float* wo  = wWl + og*512;                 // [16][32]
  const float* s1o = S1 + (size_t)b*98304 + (size_t)og*16*3072 + h*24;
  float accv[16];
  #pragma unroll
  for (int oi=0;oi<16;oi++){
    int o = og*16+oi;
    float bse = wbl[o] + bbl[o] + cbl[o] + gx*bWl[o*2] + gy*bWl[o*2+1]
              + m1*cWl[o*3] + m2*cWl[o*3+1] + m3*cWl[o*3+2];
    const float* sp = s1o + (size_t)oi*3072;
    float spec = sp[0];
    #pragma unroll
    for (int kx=1;kx<12;kx++) spec += 2.0f*(sp[2*kx]*ct[kx] - sp[2*kx+1]*st[kx]);
    accv[oi] = bse + spec;
  }
  #pragma unroll
  for (int c=0;c<32;c++){
    float xc = xv[c];
    #pragma unroll
    for (int oi=0;oi<16;oi++) accv[oi] += wo[oi*32+c]*xc;
  }
  #pragma unroll
  for (int oi=0;oi<16;oi++){
    int o = og*16+oi;
    yout[(((size_t)(b*32+o))*128+h)*128+w] = gelu_f(accv[oi]);
  }
}

// ------- head GEMM 1 (fc1, K=32): y -> A1 bf16 hi/lo [p][256], GELU --------
__global__ __launch_bounds__(256) void k_head1b(const float* __restrict__ y, const float* __restrict__ W,
                        const float* __restrict__ bias,
                        u16* __restrict__ A1h, u16* __restrict__ A1l){
  __shared__ float As[32][68];
  __shared__ float Bs[32][132];
  __shared__ float bsn[128];
  int t = threadIdx.x;
  int pg = blockIdx.x*64;
  int b = pg>>14, hw0 = pg&16383;
  int n0 = blockIdx.y*128;
  if (t < 128) bsn[t] = bias[n0 + t];
  for (int i=t;i<2048;i+=256){ int k=i>>6, pl=i&63;
    As[k][pl] = y[((size_t)(b*32+k))*16384 + hw0 + pl]; }
  for (int i=t;i<1024;i+=256){ int k=i>>5, f=i&31;
    *reinterpret_cast<float4*>(&Bs[k][f*4]) =
      *reinterpret_cast<const float4*>(&W[(size_t)k*256 + n0 + f*4]); }
  __syncthreads();
  int px = t&15, ny = t>>4;
  float acc[4][8]={};
  #pragma unroll 8
  for (int k=0;k<32;k++){
    float a[4], bb[8];
    *reinterpret_cast<float4*>(a)    = *reinterpret_cast<const float4*>(&As[k][px*4]);
    *reinterpret_cast<float4*>(bb)   = *reinterpret_cast<const float4*>(&Bs[k][ny*8]);
    *reinterpret_cast<float4*>(bb+4) = *reinterpret_cast<const float4*>(&Bs[k][ny*8+4]);
    #pragma unroll
    for (int i=0;i<4;i++)
      #pragma unroll
      for (int j=0;j<8;j++) acc[i][j] += a[i]*bb[j];
  }
  #pragma unroll
  for (int i=0;i<4;i++){
    int p = blockIdx.x*64 + px*4 + i;
    ushort8v h8, l8;
    #pragma unroll
    for (int j=0;j<8;j++){
      float v = gelu_f(acc[i][j] + bsn[ny*8+j]);
      u16 hh = f2bf(v);
      h8[j] = hh;
      l8[j] = f2bf(v - bf2f(hh));
    }
    size_t off = (size_t)p*256 + n0 + ny*8;
    *reinterpret_cast<ushort8v*>(A1h + off) = h8;
    *reinterpret_cast<ushort8v*>(A1l + off) = l8;
  }
}

// ------- W3 prep: W3[256k][128n] fp32 -> W3T hi/lo bf16 [n][256k] ----------
__global__ __launch_bounds__(256) void k_w3prep(const float* __restrict__ W3,
                        u16* __restrict__ Wh, u16* __restrict__ Wl){
  __shared__ float buf[32][132];
  int t = threadIdx.x;
  int k0 = blockIdx.x*32;          // 8 blocks
  for (int i=t;i<4096;i+=256){ int k=i>>7, n=i&127;
    buf[k][n] = W3[(size_t)(k0+k)*128 + n]; }
  __syncthreads();
  int n = t>>1, kq = t&1;
  #pragma unroll
  for (int kk=0;kk<16;kk++){
    int k = kq*16 + kk;
    float v = buf[k][n];
    u16 hh = f2bf(v);
    Wh[(size_t)n*256 + k0 + k] = hh;
    Wl[(size_t)n*256 + k0 + k] = f2bf(v - bf2f(hh));
  }
}

// ------- fc3 via MFMA bf16x3: A1[p][256] x W3T[n][256] -> A2[n][p], GELU ----
__global__ __launch_bounds__(256,4) void k_fc3m(const u16* __restrict__ A1h, const u16* __restrict__ A1l,
                      const u16* __restrict__ Wh, const u16* __restrict__ Wl,
                      const float* __restrict__ bias, float* __restrict__ A2){
  __shared__ u16 Lds[4][128][40];   // 80B rows (16B aligned, 2-way banks = free)
  int t = threadIdx.x;
  int w = t>>6, lane = t&63;
  int lr = lane&15, lg = lane>>4;
  int pr = w>>1, nc = w&1;
  int pblk = blockIdx.x*128;
  // staging: wave w owns array w (0:Ah 1:Al 2:Wh 3:Wl)
  const u16* gsrc = (w==0)? A1h : (w==1)? A1l : (w==2)? Wh : Wl;
  size_t growbase = (w<2)? (size_t)pblk*256 : 0;
  int sp = lane>>2, skc = lane&3;   // 16 rows x 4 chunks of 16B per issue
  f32x4 acc[4][4];
  #pragma unroll
  for (int i=0;i<4;i++)
    #pragma unroll
    for (int j=0;j<4;j++) acc[i][j] = (f32x4){0.f,0.f,0.f,0.f};

  for (int kt=0; kt<8; ++kt){
    int k0 = kt*32;
    #pragma unroll
    for (int r=0;r<8;r++){
      int row = r*16 + sp;
      short8v v = *reinterpret_cast<const short8v*>(gsrc + growbase + (size_t)row*256 + k0 + skc*8);
      *reinterpret_cast<short8v*>(&Lds[w][row][skc*8]) = v;
    }
    __syncthreads();
    short8v bh[4], bl[4];
    #pragma unroll
    for (int j=0;j<4;j++){
      int row = nc*64 + j*16 + lr;
      bh[j] = *reinterpret_cast<const short8v*>(&Lds[2][row][lg*8]);
      bl[j] = *reinterpret_cast<const short8v*>(&Lds[3][row][lg*8]);
    }
    #pragma unroll
    for (int i=0;i<4;i++){
      int row = pr*64 + i*16 + lr;
      short8v ah = *reinterpret_cast<const short8v*>(&Lds[0][row][lg*8]);
      short8v al = *reinterpret_cast<const short8v*>(&Lds[1][row][lg*8]);
      #pragma unroll
      for (int j=0;j<4;j++){
        acc[i][j] = __builtin_amdgcn_mfma_f32_16x16x32_bf16(ah, bh[j], acc[i][j], 0, 0, 0);
        acc[i][j] = __builtin_amdgcn_mfma_f32_16x16x32_bf16(ah, bl[j], acc[i][j], 0, 0, 0);
        acc[i][j] = __builtin_amdgcn_mfma_f32_16x16x32_bf16(al, bh[j], acc[i][j], 0, 0, 0);
      }
    }
    __syncthreads();
  }
  // epilogue: C/D layout col = lane&15 (n), row = 4*(lane>>4)+reg (p)
  #pragma unroll
  for (int j=0;j<4;j++){
    int n = nc*64 + j*16 + lr;
    float bn = bias[n];
    #pragma unroll
    for (int i=0;i<4;i++){
      int p = pblk + pr*64 + i*16 + lg*4;
      float4 v;
      v.x = gelu_f(acc[i][j][0] + bn);
      v.y = gelu_f(acc[i][j][1] + bn);
      v.z = gelu_f(acc[i][j][2] + bn);
      v.w = gelu_f(acc[i][j][3] + bn);
      *reinterpret_cast<float4*>(&A2[(size_t)n*131072 + p]) = v;
    }
  }
}

// ------ fused fc4+fc5: A2[k][p] @ W4[128,128]+b4, dot w5, +b5 -> out[p] -----
__global__ __launch_bounds__(256) void k_last(const float* __restrict__ A, const float* __restrict__ W4,
                   const float* __restrict__ b4, const float* __restrict__ w5,
                   const float* __restrict__ b5, float* __restrict__ out){
  __shared__ __align__(16) float As[32][132];
  __shared__ __align__(16) float Bs[32][132];
  __shared__ float b4s[128], w5s[128];
  __shared__ float part[4][128];
  int t=threadIdx.x;
  if (t<128){ b4s[t]=b4[t]; w5s[t]=w5[t]; }
  size_t p0 = (size_t)blockIdx.x*128;
  int tx=t&15, ty=t>>4;
  float acc[8][8]={};
  for (int kc=0;kc<128;kc+=32){
    for (int i=t;i<1024;i+=256){ int k=i>>5, f=i&31;
      *reinterpret_cast<float4*>(&As[k][f*4]) =
        *reinterpret_cast<const float4*>(&A[(size_t)(kc+k)*131072 + p0 + f*4]); }
    for (int i=t;i<1024;i+=256){ int k=i>>5, f=i&31;
      *reinterpret_cast<float4*>(&Bs[k][f*4]) =
        *reinterpret_cast<const float4*>(&W4[(size_t)(kc+k)*128 + f*4]); }
    __syncthreads();
    #pragma unroll 8
    for (int k=0;k<32;k++){
      float a[8], bb[8];
      *reinterpret_cast<float4*>(a)    = *reinterpret_cast<const float4*>(&As[k][tx*4]);
      *reinterpret_cast<float4*>(a+4)  = *reinterpret_cast<const float4*>(&As[k][64+tx*4]);
      *reinterpret_cast<float4*>(bb)   = *reinterpret_cast<const float4*>(&Bs[k][ty*4]);
      *reinterpret_cast<float4*>(bb+4) = *reinterpret_cast<const float4*>(&Bs[k][64+ty*4]);
      #pragma unroll
      for (int i=0;i<8;i++)
        #pragma unroll
        for (int j=0;j<8;j++) acc[i][j] += a[i]*bb[j];
    }
    __syncthreads();
  }
  float s[8];
  #pragma unroll
  for (int i=0;i<8;i++){
    float si = 0.f;
    #pragma unroll
    for (int j=0;j<8;j++){
      int n = (j<4)? ty*4+j : 64+ty*4+(j-4);
      si += (acc[i][j] + b4s[n]) * w5s[n];
    }
    si += __shfl_xor(si, 16);
    si += __shfl_xor(si, 32);
    s[i] = si;
  }
  int wv = t>>6;
  if ((t&63) < 16){
    #pragma unroll
    for (int i=0;i<8;i++){
      int m = (i<4)? tx*4+i : 64+tx*4+(i-4);
      part[wv][m] = s[i];
    }
  }
  __syncthreads();
  if (t<128){
    out[p0 + t] = part[0][t]+part[1][t]+part[2][t]+part[3][t] + b5[0];
  }
}

extern "C" void kernel_launch(void* const* d_in, const int* in_sizes, int n_in,
                              void* d_out, int out_size, void* d_ws, size_t ws_size,
                              hipStream_t stream){
  const float* x     = (const float*)d_in[0];
  const float* fc0_W = (const float*)d_in[1];
  const float* fc0_b = (const float*)d_in[2];
  const float* spec_w= (const float*)d_in[3];
  const float* wW    = (const float*)d_in[4];
  const float* wb    = (const float*)d_in[5];
  const float* bW    = (const float*)d_in[6];
  const float* bb    = (const float*)d_in[7];
  const float* cW    = (const float*)d_in[8];
  const float* cb    = (const float*)d_in[9];
  const float* fc1_W = (const float*)d_in[10];
  const float* fc1_b = (const float*)d_in[11];
  const float* fc3_W = (const float*)d_in[12];
  const float* fc3_b = (const float*)d_in[13];
  const float* fc4_W = (const float*)d_in[14];
  const float* fc4_b = (const float*)d_in[15];
  const float* fc5_W = (const float*)d_in[16];
  const float* fc5_b = (const float*)d_in[17];
  float* out = (float*)d_out;
  float* ws  = (float*)d_ws;

  float* y_a = ws;                         // 4,194,304 (live until head1)
  float* y_b = y_a + 4194304;              // 4,194,304
  float* wT  = y_b + 4194304;              // 3,538,944
  float* F2  = wT + 3538944;               //   147,456
  float* G   = F2 + 147456;                //   147,456
  float* S1  = G  + 147456;                //   786,432
  // head overlay (stream-ordered reuse of dead regions):
  u16*   A1h = (u16*)y_b;                  // 33,554,432 u16 = 16,777,216 float-slots
  u16*   A1l = (u16*)(y_b + 16777216);     // 33,554,432 u16
  float* A2  = y_b + 33554432;             // 16,777,216 floats (ends at 54,525,952)
  u16*   W3h = (u16*)y_a;                  // 32,768 u16 (y_a dead after head1)
  u16*   W3l = (u16*)y_a + 32768;          // 32,768 u16

  k_fc0<<<512,256,0,stream>>>(x, fc0_W, fc0_b, y_a);
  k_wtrans<<<288,256,0,stream>>>(spec_w, wT);

  for (int l=0;l<NL;l++){
    float* yin  = (l&1)? y_b : y_a;
    float* yout = (l&1)? y_a : y_b;
    k_dft2d<<<256,256,0,stream>>>(yin, F2);
    k_mix<<<192,256,0,stream>>>(F2, wT + (size_t)l*589824, G);
    k_idfth<<<256,256,0,stream>>>(G, S1);
    k_combine<<<1024,256,0,stream>>>(yin, S1, x,
                                     wW + (size_t)l*1024, wb + (size_t)l*32,
                                     bW + (size_t)l*64,  bb + (size_t)l*32,
                                     cW + (size_t)l*96,  cb + (size_t)l*32, yout);
  }
  float* yfin = y_a;  // after 6 layers

  dim3 g1(2048,2);
  k_head1b<<<g1,256,0,stream>>>(yfin, fc1_W, fc1_b, A1h, A1l);   // reads y_a, writes A1
  k_w3prep<<<8,256,0,stream>>>(fc3_W, W3h, W3l);                 // y_a now dead
  k_fc3m<<<1024,256,0,stream>>>(A1h, A1l, W3h, W3l, fc3_b, A2);
  k_last<<<1024,256,0,stream>>>(A2, fc4_W, fc4_b, fc5_W, fc5_b, out);
}